// Round 1
// baseline (24.376 us; speedup 1.0000x reference)
//
#include <hip/hip_runtime.h>
#include <math.h>

#define S 26
#define A 5
#define C 80
#define B 64
#define T 16
#define DSR 32.0f
#define N_CELLS (S * S)          // 676
#define N_PRED (S * S * A)       // 3380
#define CONF_N (B * N_PRED)      // 216320
#define NBT (B * T)              // 1024

// ---------------- Kernel 1: sum of conf^2 over everything ----------------
__global__ void reduce_conf_sq(const float* __restrict__ conf,
                               float* __restrict__ partials) {
    __shared__ float sm[256];
    float s = 0.f;
    for (int idx = blockIdx.x * 256 + threadIdx.x; idx < CONF_N;
         idx += 256 * gridDim.x) {
        float c = conf[idx];
        s += c * c;
    }
    sm[threadIdx.x] = s;
    __syncthreads();
    for (int w = 128; w > 0; w >>= 1) {
        if (threadIdx.x < w) sm[threadIdx.x] += sm[threadIdx.x + w];
        __syncthreads();
    }
    if (threadIdx.x == 0) partials[blockIdx.x] = sm[0];
}

// ---------------- Kernel 2: per-(b,t) target assignment + loss terms -----
// ws layout for this kernel: out5[k*NBT + bt], k = 0..4
//   k=0: noobj correction (0.5*conf^2 at m!=0 anchors of winner cells)
//   k=1: obj term  0.5*(conf_best - iou_pg)^2
//   k=2: xy term   sw * bce_sum          (gated by sw>0)
//   k=3: wh term   sw * sq_sum           (gated by sw>0)
//   k=4: cls term  sum_c (cs-tl)^2       (gated by sw>0)
__global__ void assign_kernel(const float* __restrict__ conf,
                              const float* __restrict__ pred_xy,
                              const float* __restrict__ pred_wh,
                              const float* __restrict__ cls_score,
                              const float* __restrict__ true_object,
                              const float* __restrict__ true_label,
                              const float* __restrict__ anchors,
                              float* __restrict__ out5) {
    int bt = blockIdx.x * blockDim.x + threadIdx.x;
    if (bt >= NBT) return;
    int b = bt / T;
    int t = bt % T;

    const float* to = true_object + (size_t)(b * T + t) * 4;
    float gx = to[0] / DSR, gy = to[1] / DSR;
    float gw = to[2] / DSR, gh = to[3] / DSR;
    int i = (int)floorf(gx); i = min(max(i, 0), S - 1);
    int j = (int)floorf(gy); j = min(max(j, 0), S - 1);

    // winner = no later box of this image lands in the same cell (last write wins)
    bool winner = true;
    for (int t2 = t + 1; t2 < T; ++t2) {
        const float* to2 = true_object + (size_t)(b * T + t2) * 4;
        int i2 = (int)floorf(to2[0] / DSR); i2 = min(max(i2, 0), S - 1);
        int j2 = (int)floorf(to2[1] / DSR); j2 = min(max(j2, 0), S - 1);
        if (i2 == i && j2 == j) { winner = false; break; }
    }

    float noobj_corr = 0.f, obj_term = 0.f, xy_term = 0.f, wh_term = 0.f,
          cls_term = 0.f;

    if (winner) {
        // anchor-vs-gt center-aligned IoU, argmax (first max wins, like jnp.argmax)
        float iou_a[A];
        int best = 0;
        float bestv = -1.f;
        for (int a = 0; a < A; ++a) {
            float aw = anchors[a * 2 + 0], ah = anchors[a * 2 + 1];
            float inter = fminf(gw, aw) * fminf(gh, ah);
            float uni = gw * gh + aw * ah - inter;
            float v = inter / uni;
            iou_a[a] = v;
            if (v > bestv) { bestv = v; best = a; }
        }

        size_t base = (size_t)b * N_PRED + (size_t)(i * S + j) * A;

        // noobj correction: anchors where final m != 0 (best, or IoU>0.5)
        for (int a = 0; a < A; ++a) {
            if (a == best || iou_a[a] > 0.5f) {
                float c = conf[base + a];
                noobj_corr += 0.5f * c * c;
            }
        }

        // obj: m==1 at best anchor, piou = center IoU(pred_wh@best, gt wh)
        float pw = pred_wh[(base + best) * 2 + 0];
        float ph = pred_wh[(base + best) * 2 + 1];
        float inter = fminf(pw, gw) * fminf(ph, gh);
        float uni = pw * ph + gw * gh - inter;
        float iou_pg = inter / uni;
        float cbest = conf[base + best];
        float d = cbest - iou_pg;
        obj_term = 0.5f * d * d;

        float sw = 2.0f - (gw / (float)S) * (gh / (float)S);
        if (sw > 0.f) {
            // fm quirk: fm[n] = fm_cord[n mod 676], n = (i*S+j)*A + best
            int n = (i * S + j) * A + best;
            int p = n % N_CELLS;
            float fm0 = (float)(p / S);
            float fm1 = (float)(p % S);
            float px = pred_xy[(base + best) * 2 + 0];
            float py = pred_xy[(base + best) * 2 + 1];
            float x0 = px - fm0, t0 = gx - fm0;
            float x1 = py - fm1, t1 = gy - fm1;
            float bce0 = fmaxf(x0, 0.f) - x0 * t0 + log1pf(expf(-fabsf(x0)));
            float bce1 = fmaxf(x1, 0.f) - x1 * t1 + log1pf(expf(-fabsf(x1)));
            xy_term = sw * (bce0 + bce1);
            float dw = pw - gw, dh = ph - gh;
            wh_term = sw * (dw * dw + dh * dh);

            const float* cs = cls_score + (base + best) * C;
            const float* tl = true_label + (size_t)(b * T + t) * C;
            float sacc = 0.f;
            for (int c = 0; c < C; ++c) {
                float dd = cs[c] - tl[c];
                sacc += dd * dd;
            }
            cls_term = sacc;
        }
    }

    out5[0 * NBT + bt] = noobj_corr;
    out5[1 * NBT + bt] = obj_term;
    out5[2 * NBT + bt] = xy_term;
    out5[3 * NBT + bt] = wh_term;
    out5[4 * NBT + bt] = cls_term;
}

// ---------------- Kernel 3: finalize ----------------
// ws layout: [0,256) conf partials; [256, 256+5*NBT) the five term arrays
__global__ void finalize_kernel(const float* __restrict__ ws,
                                float* __restrict__ out) {
    __shared__ float sm[256];
    int tid = threadIdx.x;
    float sums[6];

    // conf^2 total
    {
        sm[tid] = ws[tid];
        __syncthreads();
        for (int w = 128; w > 0; w >>= 1) {
            if (tid < w) sm[tid] += sm[tid + w];
            __syncthreads();
        }
        sums[0] = sm[0];
        __syncthreads();
    }
    for (int k = 0; k < 5; ++k) {
        const float* p = ws + 256 + k * NBT;
        float v = p[tid] + p[tid + 256] + p[tid + 512] + p[tid + 768];
        sm[tid] = v;
        __syncthreads();
        for (int w = 128; w > 0; w >>= 1) {
            if (tid < w) sm[tid] += sm[tid + w];
            __syncthreads();
        }
        sums[1 + k] = sm[0];
        __syncthreads();
    }

    if (tid == 0) {
        const float invB = 1.0f / (float)B;
        float noobj = (0.5f * sums[0] - sums[1]) * invB;      // SCALE_NOOBJ = 1
        float obj   = 5.0f * sums[2] * invB;                  // SCALE_OBJ * 0.5*(...)^2 already has 0.5
        float xy    = 5.0f * 0.5f * sums[3] * invB;
        float wh    = 5.0f * 0.5f * sums[4] * invB;
        float score = 5.0f * 0.5f * sums[5] * invB;
        out[0] = score;          // total_loss (overwritten by score_loss in ref)
        out[1] = noobj * 0.25f;
        out[2] = obj * 0.25f;
        out[3] = score * 0.25f;
        out[4] = xy * 0.25f;
        out[5] = wh * 0.25f;
    }
}

extern "C" void kernel_launch(void* const* d_in, const int* in_sizes, int n_in,
                              void* d_out, int out_size, void* d_ws, size_t ws_size,
                              hipStream_t stream) {
    // setup_inputs order:
    // 0: epoch (int, unused)
    // 1: conf        [B,S,S,A,1]
    // 2: pred_xy     [B,S,S,A,2]
    // 3: pred_wh     [B,S,S,A,2]
    // 4: cls_score   [B,S,S,A,C]
    // 5: true_object [B,T,4]
    // 6: true_label  [B,T,C]
    // 7: fm_cord     [S*S,2] (recomputed on device, unused)
    // 8: anchors     [A,2]
    const float* conf        = (const float*)d_in[1];
    const float* pred_xy     = (const float*)d_in[2];
    const float* pred_wh     = (const float*)d_in[3];
    const float* cls_score   = (const float*)d_in[4];
    const float* true_object = (const float*)d_in[5];
    const float* true_label  = (const float*)d_in[6];
    const float* anchors     = (const float*)d_in[8];

    float* ws  = (float*)d_ws;
    float* out = (float*)d_out;

    hipLaunchKernelGGL(reduce_conf_sq, dim3(256), dim3(256), 0, stream, conf, ws);
    hipLaunchKernelGGL(assign_kernel, dim3(4), dim3(256), 0, stream,
                       conf, pred_xy, pred_wh, cls_score, true_object,
                       true_label, anchors, ws + 256);
    hipLaunchKernelGGL(finalize_kernel, dim3(1), dim3(256), 0, stream, ws, out);
}

// Round 2
// 23.198 us; speedup vs baseline: 1.0508x; 1.0508x over previous
//
#include <hip/hip_runtime.h>
#include <math.h>

#define S 26
#define A 5
#define C 80
#define B 64
#define T 16
#define DSR 32.0f
#define N_CELLS (S * S)          // 676
#define N_PRED (S * S * A)       // 3380
#define CONF_N (B * N_PRED)      // 216320
#define CONF_N4 (CONF_N / 4)     // 54080 (exact)
#define NBT (B * T)              // 1024
#define NBLK 256

// ---------------- Kernel 1: fused conf^2 reduce + target assignment -------
// partials layout: partials[k * NBLK + blockIdx], k = 0..5
//   k=0: sum conf^2
//   k=1: noobj correction (0.5*conf^2 at m!=0 anchors of winner cells)
//   k=2: obj term  0.5*(conf_best - iou_pg)^2
//   k=3: xy term   sw * bce_sum          (gated by sw>0)
//   k=4: wh term   sw * sq_sum           (gated by sw>0)
//   k=5: cls term  sum_c (cs-tl)^2       (gated by sw>0)
__global__ __launch_bounds__(256) void fused_main(
        const float* __restrict__ conf,
        const float* __restrict__ pred_xy,
        const float* __restrict__ pred_wh,
        const float* __restrict__ cls_score,
        const float* __restrict__ true_object,
        const float* __restrict__ true_label,
        const float* __restrict__ anchors,
        float* __restrict__ partials) {
    const int tid = threadIdx.x;
    const int bid = blockIdx.x;
    const int gidx = bid * 256 + tid;

    float v0 = 0.f, v1 = 0.f, v2 = 0.f, v3 = 0.f, v4 = 0.f, v5 = 0.f;

    // ---- bulk: sum of conf^2 (float4, exactly one element per thread) ----
    if (gidx < CONF_N4) {
        float4 c = ((const float4*)conf)[gidx];
        v0 = c.x * c.x + c.y * c.y + c.z * c.z + c.w * c.w;
    }

    // ---- sparse: per-(b,t) assignment (threads 0..1023 -> blocks 0..3) ----
    if (gidx < NBT) {
        const int b = gidx / T;
        const int t = gidx % T;

        const float* to = true_object + (size_t)(b * T + t) * 4;
        float gx = to[0] / DSR, gy = to[1] / DSR;
        float gw = to[2] / DSR, gh = to[3] / DSR;
        int i = (int)floorf(gx); i = min(max(i, 0), S - 1);
        int j = (int)floorf(gy); j = min(max(j, 0), S - 1);

        // winner = no later box of this image lands in the same cell
        bool winner = true;
        for (int t2 = t + 1; t2 < T; ++t2) {
            const float* to2 = true_object + (size_t)(b * T + t2) * 4;
            int i2 = (int)floorf(to2[0] / DSR); i2 = min(max(i2, 0), S - 1);
            int j2 = (int)floorf(to2[1] / DSR); j2 = min(max(j2, 0), S - 1);
            if (i2 == i && j2 == j) { winner = false; break; }
        }

        if (winner) {
            float iou_a[A];
            int best = 0;
            float bestv = -1.f;
            for (int a = 0; a < A; ++a) {
                float aw = anchors[a * 2 + 0], ah = anchors[a * 2 + 1];
                float inter = fminf(gw, aw) * fminf(gh, ah);
                float uni = gw * gh + aw * ah - inter;
                float val = inter / uni;
                iou_a[a] = val;
                if (val > bestv) { bestv = val; best = a; }
            }

            size_t base = (size_t)b * N_PRED + (size_t)(i * S + j) * A;

            for (int a = 0; a < A; ++a) {
                if (a == best || iou_a[a] > 0.5f) {
                    float c = conf[base + a];
                    v1 += 0.5f * c * c;
                }
            }

            float pw = pred_wh[(base + best) * 2 + 0];
            float ph = pred_wh[(base + best) * 2 + 1];
            float inter = fminf(pw, gw) * fminf(ph, gh);
            float uni = pw * ph + gw * gh - inter;
            float iou_pg = inter / uni;
            float cbest = conf[base + best];
            float d = cbest - iou_pg;
            v2 = 0.5f * d * d;

            float sw = 2.0f - (gw / (float)S) * (gh / (float)S);
            if (sw > 0.f) {
                // fm quirk: fm[n] = fm_cord[n mod 676], n = (i*S+j)*A + best
                int n = (i * S + j) * A + best;
                int p = n % N_CELLS;
                float fm0 = (float)(p / S);
                float fm1 = (float)(p % S);
                float px = pred_xy[(base + best) * 2 + 0];
                float py = pred_xy[(base + best) * 2 + 1];
                float x0 = px - fm0, t0 = gx - fm0;
                float x1 = py - fm1, t1 = gy - fm1;
                float bce0 = fmaxf(x0, 0.f) - x0 * t0 + log1pf(expf(-fabsf(x0)));
                float bce1 = fmaxf(x1, 0.f) - x1 * t1 + log1pf(expf(-fabsf(x1)));
                v3 = sw * (bce0 + bce1);
                float dw = pw - gw, dh = ph - gh;
                v4 = sw * (dw * dw + dh * dh);

                const float* cs = cls_score + (base + best) * C;
                const float* tl = true_label + (size_t)(b * T + t) * C;
                float sacc = 0.f;
                for (int c = 0; c < C; ++c) {
                    float dd = cs[c] - tl[c];
                    sacc += dd * dd;
                }
                v5 = sacc;
            }
        }
    }

    // ---- per-block reduce of 6 sums into partials ----
    __shared__ float sm[256];
    float vs[6] = {v0, v1, v2, v3, v4, v5};
    for (int k = 0; k < 6; ++k) {
        sm[tid] = vs[k];
        __syncthreads();
        for (int w = 128; w > 0; w >>= 1) {
            if (tid < w) sm[tid] += sm[tid + w];
            __syncthreads();
        }
        if (tid == 0) partials[k * NBLK + bid] = sm[0];
        __syncthreads();
    }
}

// ---------------- Kernel 2: finalize ----------------
__global__ __launch_bounds__(256) void finalize_kernel(
        const float* __restrict__ partials, float* __restrict__ out) {
    __shared__ float sm[256];
    const int tid = threadIdx.x;
    float sums[6];

    for (int k = 0; k < 6; ++k) {
        sm[tid] = partials[k * NBLK + tid];
        __syncthreads();
        for (int w = 128; w > 0; w >>= 1) {
            if (tid < w) sm[tid] += sm[tid + w];
            __syncthreads();
        }
        sums[k] = sm[0];
        __syncthreads();
    }

    if (tid == 0) {
        const float invB = 1.0f / (float)B;
        float noobj = (0.5f * sums[0] - sums[1]) * invB;   // SCALE_NOOBJ = 1
        float obj   = 5.0f * sums[2] * invB;               // 0.5 already applied
        float xy    = 5.0f * 0.5f * sums[3] * invB;
        float wh    = 5.0f * 0.5f * sums[4] * invB;
        float score = 5.0f * 0.5f * sums[5] * invB;
        out[0] = score;          // total_loss (overwritten by score_loss in ref)
        out[1] = noobj * 0.25f;
        out[2] = obj * 0.25f;
        out[3] = score * 0.25f;
        out[4] = xy * 0.25f;
        out[5] = wh * 0.25f;
    }
}

extern "C" void kernel_launch(void* const* d_in, const int* in_sizes, int n_in,
                              void* d_out, int out_size, void* d_ws, size_t ws_size,
                              hipStream_t stream) {
    // setup_inputs order:
    // 0: epoch (unused), 1: conf, 2: pred_xy, 3: pred_wh, 4: cls_score,
    // 5: true_object, 6: true_label, 7: fm_cord (recomputed), 8: anchors
    const float* conf        = (const float*)d_in[1];
    const float* pred_xy     = (const float*)d_in[2];
    const float* pred_wh     = (const float*)d_in[3];
    const float* cls_score   = (const float*)d_in[4];
    const float* true_object = (const float*)d_in[5];
    const float* true_label  = (const float*)d_in[6];
    const float* anchors     = (const float*)d_in[8];

    float* ws  = (float*)d_ws;   // partials: 6 * 256 floats
    float* out = (float*)d_out;

    hipLaunchKernelGGL(fused_main, dim3(NBLK), dim3(256), 0, stream,
                       conf, pred_xy, pred_wh, cls_score, true_object,
                       true_label, anchors, ws);
    hipLaunchKernelGGL(finalize_kernel, dim3(1), dim3(256), 0, stream, ws, out);
}

// Round 3
// 15.539 us; speedup vs baseline: 1.5688x; 1.4929x over previous
//
#include <hip/hip_runtime.h>
#include <math.h>

#define S 26
#define A 5
#define C 80
#define B 64
#define T 16
#define DSR 32.0f
#define N_CELLS (S * S)          // 676
#define N_PRED (S * S * A)       // 3380
#define CONF_N (B * N_PRED)      // 216320
#define CONF_N4 (CONF_N / 4)     // 54080 (exact)
#define NBT (B * T)              // 1024
#define NBLK 256

// ---------------- Kernel 1: fused conf^2 reduce + target assignment -------
// partials layout: partials[k * NBLK + blockIdx], k = 0..5
//   k=0: sum conf^2
//   k=1: noobj correction (0.5*conf^2 at m!=0 anchors of winner cells)
//   k=2: obj term  0.5*(conf_best - iou_pg)^2
//   k=3: xy term   sw * bce_sum          (gated by sw>0)
//   k=4: wh term   sw * sq_sum           (gated by sw>0)
//   k=5: cls term  sum_c (cs-tl)^2       (gated by sw>0)
__global__ __launch_bounds__(256) void fused_main(
        const float* __restrict__ conf,
        const float* __restrict__ pred_xy,
        const float* __restrict__ pred_wh,
        const float* __restrict__ cls_score,
        const float* __restrict__ true_object,
        const float* __restrict__ true_label,
        const float* __restrict__ anchors,
        float* __restrict__ partials) {
    const int tid = threadIdx.x;
    const int bid = blockIdx.x;
    const int gidx = bid * 256 + tid;

    float v0 = 0.f, v1 = 0.f, v2 = 0.f, v3 = 0.f, v4 = 0.f, v5 = 0.f;

    // ---- bulk: sum of conf^2 (float4, exactly one element per thread) ----
    if (gidx < CONF_N4) {
        float4 c = ((const float4*)conf)[gidx];
        v0 = c.x * c.x + c.y * c.y + c.z * c.z + c.w * c.w;
    }

    // ---- sparse: per-(b,t) assignment (threads of blocks 0..3) ----
    if (gidx < NBT) {
        const int b = gidx / T;
        const int t = gidx % T;

        const float* to = true_object + (size_t)(b * T + t) * 4;
        float gx = to[0] / DSR, gy = to[1] / DSR;
        float gw = to[2] / DSR, gh = to[3] / DSR;
        int i = (int)floorf(gx); i = min(max(i, 0), S - 1);
        int j = (int)floorf(gy); j = min(max(j, 0), S - 1);

        // winner = no later box of this image lands in the same cell
        bool winner = true;
        for (int t2 = t + 1; t2 < T; ++t2) {
            const float* to2 = true_object + (size_t)(b * T + t2) * 4;
            int i2 = (int)floorf(to2[0] / DSR); i2 = min(max(i2, 0), S - 1);
            int j2 = (int)floorf(to2[1] / DSR); j2 = min(max(j2, 0), S - 1);
            if (i2 == i && j2 == j) { winner = false; break; }
        }

        if (winner) {
            float iou_a[A];
            int best = 0;
            float bestv = -1.f;
            for (int a = 0; a < A; ++a) {
                float aw = anchors[a * 2 + 0], ah = anchors[a * 2 + 1];
                float inter = fminf(gw, aw) * fminf(gh, ah);
                float uni = gw * gh + aw * ah - inter;
                float val = inter / uni;
                iou_a[a] = val;
                if (val > bestv) { bestv = val; best = a; }
            }

            size_t base = (size_t)b * N_PRED + (size_t)(i * S + j) * A;

            for (int a = 0; a < A; ++a) {
                if (a == best || iou_a[a] > 0.5f) {
                    float c = conf[base + a];
                    v1 += 0.5f * c * c;
                }
            }

            float pw = pred_wh[(base + best) * 2 + 0];
            float ph = pred_wh[(base + best) * 2 + 1];
            float inter = fminf(pw, gw) * fminf(ph, gh);
            float uni = pw * ph + gw * gh - inter;
            float iou_pg = inter / uni;
            float cbest = conf[base + best];
            float d = cbest - iou_pg;
            v2 = 0.5f * d * d;

            float sw = 2.0f - (gw / (float)S) * (gh / (float)S);
            if (sw > 0.f) {
                // fm quirk: fm[n] = fm_cord[n mod 676], n = (i*S+j)*A + best
                int n = (i * S + j) * A + best;
                int p = n % N_CELLS;
                float fm0 = (float)(p / S);
                float fm1 = (float)(p % S);
                float px = pred_xy[(base + best) * 2 + 0];
                float py = pred_xy[(base + best) * 2 + 1];
                float x0 = px - fm0, t0 = gx - fm0;
                float x1 = py - fm1, t1 = gy - fm1;
                float bce0 = fmaxf(x0, 0.f) - x0 * t0 + log1pf(expf(-fabsf(x0)));
                float bce1 = fmaxf(x1, 0.f) - x1 * t1 + log1pf(expf(-fabsf(x1)));
                v3 = sw * (bce0 + bce1);
                float dw = pw - gw, dh = ph - gh;
                v4 = sw * (dw * dw + dh * dh);

                const float* cs = cls_score + (base + best) * C;
                const float* tl = true_label + (size_t)(b * T + t) * C;
                float sacc = 0.f;
                for (int c = 0; c < C; ++c) {
                    float dd = cs[c] - tl[c];
                    sacc += dd * dd;
                }
                v5 = sacc;
            }
        }
    }

    // ---- block reduce: wave shuffle butterflies, then one barrier ----
    float vs[6] = {v0, v1, v2, v3, v4, v5};
    #pragma unroll
    for (int k = 0; k < 6; ++k) {
        float v = vs[k];
        #pragma unroll
        for (int off = 32; off >= 1; off >>= 1)
            v += __shfl_xor(v, off, 64);
        vs[k] = v;   // lane-uniform within wave now
    }
    __shared__ float sm[4 * 6];
    const int wave = tid >> 6;
    const int lane = tid & 63;
    if (lane == 0) {
        #pragma unroll
        for (int k = 0; k < 6; ++k) sm[wave * 6 + k] = vs[k];
    }
    __syncthreads();
    if (tid < 6) {
        partials[tid * NBLK + bid] =
            sm[0 * 6 + tid] + sm[1 * 6 + tid] + sm[2 * 6 + tid] + sm[3 * 6 + tid];
    }
}

// ---------------- Kernel 2: finalize (single wave, no barriers) ----------
__global__ __launch_bounds__(64) void finalize_kernel(
        const float* __restrict__ partials, float* __restrict__ out) {
    const int tid = threadIdx.x;  // 0..63
    float sums[6];
    #pragma unroll
    for (int k = 0; k < 6; ++k) {
        const float* p = partials + k * NBLK;
        float v = p[tid] + p[tid + 64] + p[tid + 128] + p[tid + 192];
        #pragma unroll
        for (int off = 32; off >= 1; off >>= 1)
            v += __shfl_xor(v, off, 64);
        sums[k] = v;
    }

    if (tid == 0) {
        const float invB = 1.0f / (float)B;
        float noobj = (0.5f * sums[0] - sums[1]) * invB;   // SCALE_NOOBJ = 1
        float obj   = 5.0f * sums[2] * invB;               // 0.5 already applied
        float xy    = 5.0f * 0.5f * sums[3] * invB;
        float wh    = 5.0f * 0.5f * sums[4] * invB;
        float score = 5.0f * 0.5f * sums[5] * invB;
        out[0] = score;          // total_loss (overwritten by score_loss in ref)
        out[1] = noobj * 0.25f;
        out[2] = obj * 0.25f;
        out[3] = score * 0.25f;
        out[4] = xy * 0.25f;
        out[5] = wh * 0.25f;
    }
}

extern "C" void kernel_launch(void* const* d_in, const int* in_sizes, int n_in,
                              void* d_out, int out_size, void* d_ws, size_t ws_size,
                              hipStream_t stream) {
    // setup_inputs order:
    // 0: epoch (unused), 1: conf, 2: pred_xy, 3: pred_wh, 4: cls_score,
    // 5: true_object, 6: true_label, 7: fm_cord (recomputed), 8: anchors
    const float* conf        = (const float*)d_in[1];
    const float* pred_xy     = (const float*)d_in[2];
    const float* pred_wh     = (const float*)d_in[3];
    const float* cls_score   = (const float*)d_in[4];
    const float* true_object = (const float*)d_in[5];
    const float* true_label  = (const float*)d_in[6];
    const float* anchors     = (const float*)d_in[8];

    float* ws  = (float*)d_ws;   // partials: 6 * 256 floats
    float* out = (float*)d_out;

    hipLaunchKernelGGL(fused_main, dim3(NBLK), dim3(256), 0, stream,
                       conf, pred_xy, pred_wh, cls_score, true_object,
                       true_label, anchors, ws);
    hipLaunchKernelGGL(finalize_kernel, dim3(1), dim3(64), 0, stream, ws, out);
}